// Round 6
// baseline (11850.743 us; speedup 1.0000x reference)
//
#include <hip/hip_runtime.h>
#include <hip/hip_bf16.h>
#include <string.h>

// Problem constants
#define T_STEPS 512
#define BATCH   128
#define DIM     256
#define HID     256
#define NLAYERS 4

typedef unsigned int  uint4v  __attribute__((ext_vector_type(4)));
typedef unsigned int  uint2v  __attribute__((ext_vector_type(2)));
typedef short         short8  __attribute__((ext_vector_type(8)));
typedef float         float4v __attribute__((ext_vector_type(4)));

// ws layout (TOTAL 512KB):
//   [0, 512KB) : h exchange ring, 4 slots x (8 clusters x 16 rows x 128 pairs x 8B)
//                pair = [bf16x2 packed h | 32-bit round tag]  (tag-in-data sync)
#define SLOT_BYTES  (128 * 1024)
#define NSLOTS      4
#define HBUF_BYTES  (NSLOTS * SLOT_BYTES)

// sc0-only poll iterations before demoting to device-scope (sc0 sc1) polls.
#define FAST_ITERS  128

__device__ __forceinline__ short8 as_s8(uint4v u) {
  union { uint4v u; short8 s; } x; x.u = u; return x.s;
}
__device__ __forceinline__ float sigf(float x) {
  return 1.0f / (1.0f + __expf(-x));
}
__device__ __forceinline__ float tanh_fast(float x) {
  x = fminf(fmaxf(x, -15.0f), 15.0f);
  float e = __expf(2.0f * x);
  return (e - 1.0f) / (e + 1.0f);
}
// round-to-nearest-even f32 -> bf16 (inputs always finite here)
__device__ __forceinline__ unsigned short f2bf(float a) {
  unsigned ua = __builtin_bit_cast(unsigned, a);
  return (unsigned short)((ua + 0x7FFFu + ((ua >> 16) & 1u)) >> 16);
}
__device__ __forceinline__ unsigned pack_bf16x2(float a, float b) {
  return (unsigned)f2bf(a) | ((unsigned)f2bf(b) << 16);
}
__device__ __forceinline__ uint4v extract_frag(uint4v a, uint4v b) {
  uint4v f; f.x = a.x; f.y = a.z; f.z = b.x; f.w = b.z; return f;
}
__device__ __forceinline__ unsigned tagbad(uint4v a, uint4v b, unsigned tag) {
  return (a.y ^ tag) | (a.w ^ tag) | (b.y ^ tag) | (b.w ^ tag);
}

// 16 x 16B loads covering this lane's 8 A-fragments worth of [data|tag]
// pairs; single waitcnt. vaddr form (per-lane 64-bit address).
// SC flags parameterized: "sc0" = L1-bypass, L2-coherent (fast, XCD-local);
// "sc0 sc1" = device coherence point (slow, always-correct fallback).
#define GLD16_FLAGS(A0,B0,A1,B1,A2,B2,A3,B3,A4,B4,A5,B5,A6,B6,A7,B7, ADDR, FLAGS) \
  asm volatile(                                                             \
      "global_load_dwordx4 %0, %16, off offset:0 " FLAGS "\n\t"             \
      "global_load_dwordx4 %1, %16, off offset:16 " FLAGS "\n\t"            \
      "global_load_dwordx4 %2, %16, off offset:128 " FLAGS "\n\t"           \
      "global_load_dwordx4 %3, %16, off offset:144 " FLAGS "\n\t"           \
      "global_load_dwordx4 %4, %16, off offset:256 " FLAGS "\n\t"           \
      "global_load_dwordx4 %5, %16, off offset:272 " FLAGS "\n\t"           \
      "global_load_dwordx4 %6, %16, off offset:384 " FLAGS "\n\t"           \
      "global_load_dwordx4 %7, %16, off offset:400 " FLAGS "\n\t"           \
      "global_load_dwordx4 %8, %16, off offset:512 " FLAGS "\n\t"           \
      "global_load_dwordx4 %9, %16, off offset:528 " FLAGS "\n\t"           \
      "global_load_dwordx4 %10, %16, off offset:640 " FLAGS "\n\t"          \
      "global_load_dwordx4 %11, %16, off offset:656 " FLAGS "\n\t"          \
      "global_load_dwordx4 %12, %16, off offset:768 " FLAGS "\n\t"          \
      "global_load_dwordx4 %13, %16, off offset:784 " FLAGS "\n\t"          \
      "global_load_dwordx4 %14, %16, off offset:896 " FLAGS "\n\t"          \
      "global_load_dwordx4 %15, %16, off offset:912 " FLAGS "\n\t"          \
      "s_waitcnt vmcnt(0)"                                                  \
      : "=&v"(A0), "=&v"(B0), "=&v"(A1), "=&v"(B1),                         \
        "=&v"(A2), "=&v"(B2), "=&v"(A3), "=&v"(B3),                         \
        "=&v"(A4), "=&v"(B4), "=&v"(A5), "=&v"(B5),                         \
        "=&v"(A6), "=&v"(B6), "=&v"(A7), "=&v"(B7)                          \
      : "v"(ADDR)                                                           \
      : "memory")

// Adaptive poll: sc0-only (XCD-L2) while _it < FASTLIM; beyond that,
// device-scope sc0 sc1 (always sees MALL-visible publishes). If success
// required the fallback, FASTLIM self-demotes to 0 for all later polls.
// Stale sc0 reads can only show OLD tags (monotonic) — never false-positive.
#define POLL8T(F0,F1,F2,F3,F4,F5,F6,F7, ADDR, TAG, FASTLIM)                 \
  {                                                                         \
    uint4v _a0,_b0,_a1,_b1,_a2,_b2,_a3,_b3,_a4,_b4,_a5,_b5,_a6,_b6,_a7,_b7; \
    for (int _it = 0;; ++_it) {                                             \
      if (_it < FASTLIM) {                                                  \
        GLD16_FLAGS(_a0,_b0,_a1,_b1,_a2,_b2,_a3,_b3,                        \
                    _a4,_b4,_a5,_b5,_a6,_b6,_a7,_b7, ADDR, "sc0");          \
      } else {                                                              \
        GLD16_FLAGS(_a0,_b0,_a1,_b1,_a2,_b2,_a3,_b3,                        \
                    _a4,_b4,_a5,_b5,_a6,_b6,_a7,_b7, ADDR, "sc0 sc1");      \
      }                                                                     \
      unsigned _bad = tagbad(_a0,_b0,TAG) | tagbad(_a1,_b1,TAG) |           \
                      tagbad(_a2,_b2,TAG) | tagbad(_a3,_b3,TAG) |           \
                      tagbad(_a4,_b4,TAG) | tagbad(_a5,_b5,TAG) |           \
                      tagbad(_a6,_b6,TAG) | tagbad(_a7,_b7,TAG);            \
      if (__all((int)(_bad == 0u))) {                                       \
        if (_it >= FASTLIM) FASTLIM = 0;                                    \
        break;                                                              \
      }                                                                     \
      if (_it > (1 << 16)) break;                                           \
      if (_it >= 2) __builtin_amdgcn_s_sleep(1);                            \
    }                                                                       \
    F0 = extract_frag(_a0,_b0); F1 = extract_frag(_a1,_b1);                 \
    F2 = extract_frag(_a2,_b2); F3 = extract_frag(_a3,_b3);                 \
    F4 = extract_frag(_a4,_b4); F5 = extract_frag(_a5,_b5);                 \
    F6 = extract_frag(_a6,_b6); F7 = extract_frag(_a7,_b7);                 \
  }

// Publishes stay device-scope (sc0 sc1): visible at MALL regardless of
// workgroup->XCD placement; same-XCD consumers see the update through L2.
#define PUBLISH(ADDR, PACKED, TAG)                                          \
  {                                                                         \
    uint2v _pv; _pv.x = (PACKED); _pv.y = (TAG);                            \
    asm volatile("global_store_dwordx2 %0, %1, off sc0 sc1"                 \
                 :: "v"(ADDR), "v"(_pv) : "memory");                        \
  }

#define MFMA_K8(ACC, BARR, H0,H1,H2,H3,H4,H5,H6,H7)                                  \
  ACC = __builtin_amdgcn_mfma_f32_16x16x32_bf16(as_s8(H0), BARR[0], ACC, 0, 0, 0);   \
  ACC = __builtin_amdgcn_mfma_f32_16x16x32_bf16(as_s8(H1), BARR[1], ACC, 0, 0, 0);   \
  ACC = __builtin_amdgcn_mfma_f32_16x16x32_bf16(as_s8(H2), BARR[2], ACC, 0, 0, 0);   \
  ACC = __builtin_amdgcn_mfma_f32_16x16x32_bf16(as_s8(H3), BARR[3], ACC, 0, 0, 0);   \
  ACC = __builtin_amdgcn_mfma_f32_16x16x32_bf16(as_s8(H4), BARR[4], ACC, 0, 0, 0);   \
  ACC = __builtin_amdgcn_mfma_f32_16x16x32_bf16(as_s8(H5), BARR[5], ACC, 0, 0, 0);   \
  ACC = __builtin_amdgcn_mfma_f32_16x16x32_bf16(as_s8(H6), BARR[6], ACC, 0, 0, 0);   \
  ACC = __builtin_amdgcn_mfma_f32_16x16x32_bf16(as_s8(H7), BARR[7], ACC, 0, 0, 0);

// ---------------------------------------------------------------------------
// Main recurrent kernel. 8 clusters (batch slices of 16) x 16 wgs (each owns
// 16 hidden columns) x 256 threads (4 waves). ALL tensors are FLOAT32; bf16
// exists only as MFMA operands. Weight B-frags persist in VGPRs.
// XCD co-location: cluster id = bid & 7 — under round-robin block->XCD
// dispatch all 16 wgs of a cluster share one XCD, so sc0-only polls are
// served by that XCD's L2 (~4x lower latency than MALL). Placement is a
// PERFORMANCE heuristic only; the adaptive sc0->sc0sc1 poll fallback keeps
// correctness placement-independent.
// Wave roles: v0: r-gate + Tr_i; v1: z-gate + Tz_i; v2: l-gate + Tn_i;
// v3: Ch, Cx, Wt (round A only).
// Cross-wg h exchange: tag-in-data ring (4 slots). Publisher at round r
// stores [bf16x2 | tag=r+1] 8B pairs (sc0 sc1, fire-and-forget). Consumer
// at round r polls slot (r-1)&3 until all tags == r. No resets, no ABA
// (slot overwrite at tag r+4 transitively requires all wgs consumed tag r).
// ---------------------------------------------------------------------------
__launch_bounds__(256, 1)
__global__ void rnn_main(const float* __restrict__ x,
                         const int* __restrict__ lengths,
                         const float* __restrict__ Wr,
                         const float* __restrict__ Wz,
                         const float* __restrict__ Wl,
                         const float* __restrict__ Wt,
                         const float* __restrict__ Cx,
                         const float* __restrict__ Ch,
                         const float* __restrict__ Tr,
                         const float* __restrict__ Tz,
                         const float* __restrict__ Tn,
                         unsigned char* __restrict__ hbuf,
                         float* __restrict__ out) {
  const int tid  = threadIdx.x;
  const int lane = tid & 63;
  const int v    = tid >> 6;
  const int bid  = blockIdx.x;
  const int c    = bid & 7;    // cluster (batch slice) == XCD under % dispatch
  const int w    = bid >> 3;   // column-chunk owner within cluster

  __shared__ float tiles[6][16 * 20];  // col-major, col stride 20
  __shared__ float h_own[256];
  __shared__ int   len_sh[16];

  // ---- load + convert persistent weight B-fragments (one-time gather) ----
  // Fragment layout: lane l holds B[k = kt*32 + (l>>4)*8 + j][col0 + (l&15)].
  // Matrix ids: 0..2 = W{r,z,l}[256:512] (h-part), 3 = Ch, 4..6 = W{r,z,l}
  // [0:256] (x-part), 7 = Cx, 8 = Wt, 9..12 = Tr_i, 13..16 = Tz_i,
  // 17..20 = Tn_i.
  short8 Wf[6][8];
  {
    const int SCHED[4][6] = {{0, 4, 9, 10, 11, 12},
                             {1, 5, 13, 14, 15, 16},
                             {2, 6, 17, 18, 19, 20},
                             {3, 7, 8, 3, 3, 3}};
    const int colg = w * 16 + (lane & 15);
#pragma unroll
    for (int s = 0; s < 6; ++s) {
      const int m = SCHED[v][s];
      const float* base;
      int ro = 0;
      if      (m == 0)  { base = Wr; ro = 256; }
      else if (m == 1)  { base = Wz; ro = 256; }
      else if (m == 2)  { base = Wl; ro = 256; }
      else if (m == 3)  { base = Ch; }
      else if (m == 4)  { base = Wr; }
      else if (m == 5)  { base = Wz; }
      else if (m == 6)  { base = Wl; }
      else if (m == 7)  { base = Cx; }
      else if (m == 8)  { base = Wt; }
      else if (m <= 12) { base = Tr + (size_t)(m - 9)  * HID * HID; }
      else if (m <= 16) { base = Tz + (size_t)(m - 13) * HID * HID; }
      else              { base = Tn + (size_t)(m - 17) * HID * HID; }
#pragma unroll
      for (int kt = 0; kt < 8; ++kt) {
        const int k0 = ro + kt * 32 + (lane >> 4) * 8;
        short8 f;
#pragma unroll
        for (int j = 0; j < 8; ++j)
          f[j] = (short)f2bf(base[(size_t)(k0 + j) * HID + colg]);
        Wf[s][kt] = f;
      }
    }
  }

  if (tid < 16) len_sh[tid] = lengths[c * 16 + tid];
  __syncthreads();

  const int row = tid >> 4;
  const int col = tid & 15;
  const int mylen = len_sh[row];
  const int ci = col * 20 + row;

  float hreg = 0.0f, hprev = 0.0f;
  int fastlim = FAST_ITERS;  // adaptive poll scope (self-demotes to 0)

  // lane byte offset into an h slot for A-frag [data|tag] pair loads:
  // pairs laid out [c*16+row][128 pairs]; lane reads row (lane&15),
  // quarter (lane>>4): base = row*1024 + (lane>>4)*32, frag kt at +kt*128.
  const unsigned vh = (unsigned)((c * 16 + (lane & 15)) * 1024 + (lane >> 4) * 32);
  // per-thread publish offset (tid<128): row=tid>>3, colpair=tid&7
  const unsigned pub_off =
      (unsigned)(((c * 16 + (tid >> 3)) * 128 + w * 8 + (tid & 7)) * 8);
  const float* xbase =
      x + ((size_t)c * 16 + (lane & 15)) * DIM + (lane >> 4) * 8;

  for (int t = 0; t < T_STEPS; ++t) {
    const int r0 = t * 5;
    // ======================= round A (cell gates) =======================
    {
      const float* xp = xbase + (size_t)t * BATCH * DIM;
      uint4v xf[8];
#pragma unroll
      for (int kt = 0; kt < 8; ++kt) {
        float4v xa = *(const float4v*)(xp + kt * 32);
        float4v xb = *(const float4v*)(xp + kt * 32 + 4);
        uint4v f;
        f.x = pack_bf16x2(xa.x, xa.y);
        f.y = pack_bf16x2(xa.z, xa.w);
        f.z = pack_bf16x2(xb.x, xb.y);
        f.w = pack_bf16x2(xb.z, xb.w);
        xf[kt] = f;
      }

      float4v a0 = {0.f, 0.f, 0.f, 0.f};
      float4v a1 = {0.f, 0.f, 0.f, 0.f};
      float4v a2 = {0.f, 0.f, 0.f, 0.f};
      // x-dependent MFMAs first: they overlap the h poll below.
      if (v < 3) {
#pragma unroll
        for (int kt = 0; kt < 8; ++kt)
          a0 = __builtin_amdgcn_mfma_f32_16x16x32_bf16(as_s8(xf[kt]), Wf[1][kt], a0, 0, 0, 0);
      } else {
#pragma unroll
        for (int kt = 0; kt < 8; ++kt)
          a1 = __builtin_amdgcn_mfma_f32_16x16x32_bf16(as_s8(xf[kt]), Wf[1][kt], a1, 0, 0, 0);
#pragma unroll
        for (int kt = 0; kt < 8; ++kt)
          a2 = __builtin_amdgcn_mfma_f32_16x16x32_bf16(as_s8(xf[kt]), Wf[2][kt], a2, 0, 0, 0);
      }
      uint4v h0, h1, h2, h3, h4, h5, h6, h7;
      {
        const unsigned char* ap =
            hbuf + (size_t)((r0 - 1) & 3) * SLOT_BYTES + vh;
        POLL8T(h0, h1, h2, h3, h4, h5, h6, h7, ap, (unsigned)r0, fastlim);
      }
      MFMA_K8(a0, Wf[0], h0, h1, h2, h3, h4, h5, h6, h7);
      {
        float* tp = &tiles[(v < 3) ? v : 3][(lane & 15) * 20 + (lane >> 4) * 4];
        *(float4v*)tp = a0;
        if (v == 3) {
          *(float4v*)&tiles[4][(lane & 15) * 20 + (lane >> 4) * 4] = a1;
          *(float4v*)&tiles[5][(lane & 15) * 20 + (lane >> 4) * 4] = a2;
        }
      }
      __syncthreads();
      float rp  = tiles[0][ci], zp = tiles[1][ci], lp = tiles[2][ci];
      float chv = tiles[3][ci], xcv = tiles[4][ci], xwv = tiles[5][ci];
      float r  = sigf(rp), z = sigf(zp), lg = sigf(lp);
      float n  = tanh_fast(xcv + r * chv) + lg * xwv;
      hreg = (1.0f - z) * hreg + z * n;
      h_own[tid] = hreg;
      __syncthreads();
      if (tid < 128) {
        float2 hv = *(const float2*)&h_own[(tid >> 3) * 16 + (tid & 7) * 2];
        unsigned char* pp = hbuf + (size_t)(r0 & 3) * SLOT_BYTES + pub_off;
        PUBLISH(pp, pack_bf16x2(hv.x, hv.y), (unsigned)(r0 + 1));
      }
    }
    // ======================= transition layers =======================
#pragma unroll
    for (int i = 0; i < NLAYERS; ++i) {
      const int ri = r0 + 1 + i;
      if (v < 3) {
        uint4v h0, h1, h2, h3, h4, h5, h6, h7;
        const unsigned char* ap =
            hbuf + (size_t)((ri - 1) & 3) * SLOT_BYTES + vh;
        POLL8T(h0, h1, h2, h3, h4, h5, h6, h7, ap, (unsigned)ri, fastlim);
        float4v a = {0.f, 0.f, 0.f, 0.f};
        MFMA_K8(a, Wf[2 + i], h0, h1, h2, h3, h4, h5, h6, h7);
        *(float4v*)&tiles[v][(lane & 15) * 20 + (lane >> 4) * 4] = a;
      }
      __syncthreads();
      float rr = sigf(tiles[0][ci]);
      float zz = sigf(tiles[1][ci]);
      float nn = tanh_fast(rr * tiles[2][ci]);
      hreg = (1.0f - zz) * nn + zz * hreg;
      if (i == NLAYERS - 1) {
        const bool act = (t < mylen);
        float hv = act ? hreg : hprev;   // freeze h past sequence end
        float ov = act ? hreg : 0.0f;    // out = m ? hn : 0
        hreg = hv;
        hprev = hv;
        out[((size_t)t * BATCH + c * 16 + row) * HID + w * 16 + col] = ov;
      }
      h_own[tid] = hreg;
      __syncthreads();
      if (tid < 128) {
        float2 hv2 = *(const float2*)&h_own[(tid >> 3) * 16 + (tid & 7) * 2];
        unsigned char* pp = hbuf + (size_t)(ri & 3) * SLOT_BYTES + pub_off;
        PUBLISH(pp, pack_bf16x2(hv2.x, hv2.y), (unsigned)(ri + 1));
      }
    }
  }
}

extern "C" void kernel_launch(void* const* d_in, const int* in_sizes, int n_in,
                              void* d_out, int out_size, void* d_ws, size_t ws_size,
                              hipStream_t stream) {
  (void)in_sizes; (void)n_in; (void)out_size; (void)ws_size;
  const float* x        = (const float*)d_in[0];
  const int* lengths    = (const int*)d_in[1];
  const float* Wr       = (const float*)d_in[2];
  const float* Wz       = (const float*)d_in[3];
  const float* Wl       = (const float*)d_in[4];
  const float* Wt       = (const float*)d_in[5];
  const float* Cx       = (const float*)d_in[6];
  const float* Ch       = (const float*)d_in[7];
  const float* Tr       = (const float*)d_in[8];
  const float* Tz       = (const float*)d_in[9];
  const float* Tn       = (const float*)d_in[10];

  unsigned char* hbuf = (unsigned char*)d_ws;

  // Ring init: all slots zero. tag 0 == "round -1 published"; slot 3 data
  // (zeros) is exactly h0. Must re-run every launch (ws is re-poisoned).
  hipMemsetAsync(hbuf, 0x00, HBUF_BYTES, stream);

  rnn_main<<<dim3(128), dim3(256), 0, stream>>>(
      x, lengths, Wr, Wz, Wl, Wt, Cx, Ch, Tr, Tz, Tn,
      hbuf, (float*)d_out);
}

// Round 7
// 8928.020 us; speedup vs baseline: 1.3274x; 1.3274x over previous
//
#include <hip/hip_runtime.h>
#include <hip/hip_bf16.h>
#include <string.h>

// Problem constants
#define T_STEPS 512
#define BATCH   128
#define DIM     256
#define HID     256
#define NLAYERS 4

typedef unsigned int  uint4v  __attribute__((ext_vector_type(4)));
typedef unsigned int  uint2v  __attribute__((ext_vector_type(2)));
typedef short         short8  __attribute__((ext_vector_type(8)));
typedef float         float4v __attribute__((ext_vector_type(4)));

// ws layout (TOTAL 512KB):
//   [0, 512KB) : h exchange ring, 4 slots x (8 clusters x 16 rows x 128 pairs x 8B)
//                pair = [bf16x2 packed h | 32-bit round tag]  (tag-in-data sync)
#define SLOT_BYTES  (128 * 1024)
#define NSLOTS      4
#define HBUF_BYTES  (NSLOTS * SLOT_BYTES)

__device__ __forceinline__ short8 as_s8(uint4v u) {
  union { uint4v u; short8 s; } x; x.u = u; return x.s;
}
__device__ __forceinline__ float sigf(float x) {
  return 1.0f / (1.0f + __expf(-x));
}
__device__ __forceinline__ float tanh_fast(float x) {
  x = fminf(fmaxf(x, -15.0f), 15.0f);
  float e = __expf(2.0f * x);
  return (e - 1.0f) / (e + 1.0f);
}
// round-to-nearest-even f32 -> bf16 (inputs always finite here)
__device__ __forceinline__ unsigned short f2bf(float a) {
  unsigned ua = __builtin_bit_cast(unsigned, a);
  return (unsigned short)((ua + 0x7FFFu + ((ua >> 16) & 1u)) >> 16);
}
__device__ __forceinline__ unsigned pack_bf16x2(float a, float b) {
  return (unsigned)f2bf(a) | ((unsigned)f2bf(b) << 16);
}
__device__ __forceinline__ uint4v extract_frag(uint4v a, uint4v b) {
  uint4v f; f.x = a.x; f.y = a.z; f.z = b.x; f.w = b.z; return f;
}
__device__ __forceinline__ unsigned tagbad(uint4v a, uint4v b, unsigned tag) {
  return (a.y ^ tag) | (a.w ^ tag) | (b.y ^ tag) | (b.w ^ tag);
}

// 16 device-scope (sc0 sc1) 16B loads covering this lane's 8 A-fragments
// worth of [data|tag] pairs; single waitcnt. vaddr form (per-lane 64b addr).
#define GLD16(A0,B0,A1,B1,A2,B2,A3,B3,A4,B4,A5,B5,A6,B6,A7,B7, ADDR)       \
  asm volatile(                                                             \
      "global_load_dwordx4 %0, %16, off offset:0 sc0 sc1\n\t"               \
      "global_load_dwordx4 %1, %16, off offset:16 sc0 sc1\n\t"              \
      "global_load_dwordx4 %2, %16, off offset:128 sc0 sc1\n\t"             \
      "global_load_dwordx4 %3, %16, off offset:144 sc0 sc1\n\t"             \
      "global_load_dwordx4 %4, %16, off offset:256 sc0 sc1\n\t"             \
      "global_load_dwordx4 %5, %16, off offset:272 sc0 sc1\n\t"             \
      "global_load_dwordx4 %6, %16, off offset:384 sc0 sc1\n\t"             \
      "global_load_dwordx4 %7, %16, off offset:400 sc0 sc1\n\t"             \
      "global_load_dwordx4 %8, %16, off offset:512 sc0 sc1\n\t"             \
      "global_load_dwordx4 %9, %16, off offset:528 sc0 sc1\n\t"             \
      "global_load_dwordx4 %10, %16, off offset:640 sc0 sc1\n\t"            \
      "global_load_dwordx4 %11, %16, off offset:656 sc0 sc1\n\t"            \
      "global_load_dwordx4 %12, %16, off offset:768 sc0 sc1\n\t"            \
      "global_load_dwordx4 %13, %16, off offset:784 sc0 sc1\n\t"            \
      "global_load_dwordx4 %14, %16, off offset:896 sc0 sc1\n\t"            \
      "global_load_dwordx4 %15, %16, off offset:912 sc0 sc1\n\t"            \
      "s_waitcnt vmcnt(0)"                                                  \
      : "=&v"(A0), "=&v"(B0), "=&v"(A1), "=&v"(B1),                         \
        "=&v"(A2), "=&v"(B2), "=&v"(A3), "=&v"(B3),                         \
        "=&v"(A4), "=&v"(B4), "=&v"(A5), "=&v"(B5),                         \
        "=&v"(A6), "=&v"(B6), "=&v"(A7), "=&v"(B7)                          \
      : "v"(ADDR)                                                           \
      : "memory")

// Poll until every consumed pair carries tag==TAG, then unpack 8 A-frags.
// Hot spin for 16 iters, then s_sleep(1) backoff. Stale reads only show OLD
// tags (monotonic) — never false-positive.
#define POLL8T(F0,F1,F2,F3,F4,F5,F6,F7, ADDR, TAG)                          \
  {                                                                         \
    uint4v _a0,_b0,_a1,_b1,_a2,_b2,_a3,_b3,_a4,_b4,_a5,_b5,_a6,_b6,_a7,_b7; \
    for (int _it = 0;; ++_it) {                                             \
      GLD16(_a0,_b0,_a1,_b1,_a2,_b2,_a3,_b3,_a4,_b4,_a5,_b5,_a6,_b6,_a7,_b7,\
            ADDR);                                                          \
      unsigned _bad = tagbad(_a0,_b0,TAG) | tagbad(_a1,_b1,TAG) |           \
                      tagbad(_a2,_b2,TAG) | tagbad(_a3,_b3,TAG) |           \
                      tagbad(_a4,_b4,TAG) | tagbad(_a5,_b5,TAG) |           \
                      tagbad(_a6,_b6,TAG) | tagbad(_a7,_b7,TAG);            \
      if (__all((int)(_bad == 0u)) || _it > (1 << 16)) break;               \
      if (_it >= 16) __builtin_amdgcn_s_sleep(1);                           \
    }                                                                       \
    F0 = extract_frag(_a0,_b0); F1 = extract_frag(_a1,_b1);                 \
    F2 = extract_frag(_a2,_b2); F3 = extract_frag(_a3,_b3);                 \
    F4 = extract_frag(_a4,_b4); F5 = extract_frag(_a5,_b5);                 \
    F6 = extract_frag(_a6,_b6); F7 = extract_frag(_a7,_b7);                 \
  }

#define PUBLISH(ADDR, PACKED, TAG)                                          \
  {                                                                         \
    uint2v _pv; _pv.x = (PACKED); _pv.y = (TAG);                            \
    asm volatile("global_store_dwordx2 %0, %1, off sc0 sc1"                 \
                 :: "v"(ADDR), "v"(_pv) : "memory");                        \
  }

#define MFMA_K8(ACC, BARR, H0,H1,H2,H3,H4,H5,H6,H7)                                  \
  ACC = __builtin_amdgcn_mfma_f32_16x16x32_bf16(as_s8(H0), BARR[0], ACC, 0, 0, 0);   \
  ACC = __builtin_amdgcn_mfma_f32_16x16x32_bf16(as_s8(H1), BARR[1], ACC, 0, 0, 0);   \
  ACC = __builtin_amdgcn_mfma_f32_16x16x32_bf16(as_s8(H2), BARR[2], ACC, 0, 0, 0);   \
  ACC = __builtin_amdgcn_mfma_f32_16x16x32_bf16(as_s8(H3), BARR[3], ACC, 0, 0, 0);   \
  ACC = __builtin_amdgcn_mfma_f32_16x16x32_bf16(as_s8(H4), BARR[4], ACC, 0, 0, 0);   \
  ACC = __builtin_amdgcn_mfma_f32_16x16x32_bf16(as_s8(H5), BARR[5], ACC, 0, 0, 0);   \
  ACC = __builtin_amdgcn_mfma_f32_16x16x32_bf16(as_s8(H6), BARR[6], ACC, 0, 0, 0);   \
  ACC = __builtin_amdgcn_mfma_f32_16x16x32_bf16(as_s8(H7), BARR[7], ACC, 0, 0, 0);

// ---------------------------------------------------------------------------
// Main recurrent kernel. 8 clusters (batch slices of 16) x 16 wgs (each owns
// 16 hidden columns) x 256 threads (4 waves). ALL tensors are FLOAT32; bf16
// exists only as MFMA operands. Weight B-frags persist in VGPRs.
// R7 sync-path surgery:
//  * ONE wave (v0) polls per wg; A-frags broadcast to waves 1-2 via LDS
//    (frags are wave-invariant). 3-4x less poll traffic, fewer spinners.
//  * Publish IMMEDIATELY after combine: __shfl_xor pairs even/odd columns,
//    even threads store [bf16x2|tag]. Second barrier + h_own LDS gather
//    deleted -> publish lands ~600 cyc earlier on the critical path.
// Cross-wg h exchange: tag-in-data ring (4 slots). Publisher at round r
// stores [bf16x2 | tag=r+1] 8B pairs (sc0 sc1, fire-and-forget). Consumer
// at round r polls slot (r-1)&3 until all tags == r. No resets, no ABA
// (slot overwrite at tag r+4 transitively requires all wgs consumed tag r).
// ---------------------------------------------------------------------------
__launch_bounds__(256, 1)
__global__ void rnn_main(const float* __restrict__ x,
                         const int* __restrict__ lengths,
                         const float* __restrict__ Wr,
                         const float* __restrict__ Wz,
                         const float* __restrict__ Wl,
                         const float* __restrict__ Wt,
                         const float* __restrict__ Cx,
                         const float* __restrict__ Ch,
                         const float* __restrict__ Tr,
                         const float* __restrict__ Tz,
                         const float* __restrict__ Tn,
                         unsigned char* __restrict__ hbuf,
                         float* __restrict__ out) {
  const int tid  = threadIdx.x;
  const int lane = tid & 63;
  const int v    = tid >> 6;
  const int bid  = blockIdx.x;
  const int c    = bid & 7;    // cluster (batch slice)
  const int w    = bid >> 3;   // column-chunk owner within cluster

  __shared__ float  tiles[6][16 * 20];  // col-major, col stride 20
  __shared__ uint4v hsh[8][64];         // polled A-frag broadcast (8 KB)
  __shared__ int    len_sh[16];

  // ---- load + convert persistent weight B-fragments (one-time gather) ----
  // Fragment layout: lane l holds B[k = kt*32 + (l>>4)*8 + j][col0 + (l&15)].
  // Matrix ids: 0..2 = W{r,z,l}[256:512] (h-part), 3 = Ch, 4..6 = W{r,z,l}
  // [0:256] (x-part), 7 = Cx, 8 = Wt, 9..12 = Tr_i, 13..16 = Tz_i,
  // 17..20 = Tn_i.
  short8 Wf[6][8];
  {
    const int SCHED[4][6] = {{0, 4, 9, 10, 11, 12},
                             {1, 5, 13, 14, 15, 16},
                             {2, 6, 17, 18, 19, 20},
                             {3, 7, 8, 3, 3, 3}};
    const int colg = w * 16 + (lane & 15);
#pragma unroll
    for (int s = 0; s < 6; ++s) {
      const int m = SCHED[v][s];
      const float* base;
      int ro = 0;
      if      (m == 0)  { base = Wr; ro = 256; }
      else if (m == 1)  { base = Wz; ro = 256; }
      else if (m == 2)  { base = Wl; ro = 256; }
      else if (m == 3)  { base = Ch; }
      else if (m == 4)  { base = Wr; }
      else if (m == 5)  { base = Wz; }
      else if (m == 6)  { base = Wl; }
      else if (m == 7)  { base = Cx; }
      else if (m == 8)  { base = Wt; }
      else if (m <= 12) { base = Tr + (size_t)(m - 9)  * HID * HID; }
      else if (m <= 16) { base = Tz + (size_t)(m - 13) * HID * HID; }
      else              { base = Tn + (size_t)(m - 17) * HID * HID; }
#pragma unroll
      for (int kt = 0; kt < 8; ++kt) {
        const int k0 = ro + kt * 32 + (lane >> 4) * 8;
        short8 f;
#pragma unroll
        for (int j = 0; j < 8; ++j)
          f[j] = (short)f2bf(base[(size_t)(k0 + j) * HID + colg]);
        Wf[s][kt] = f;
      }
    }
  }

  if (tid < 16) len_sh[tid] = lengths[c * 16 + tid];
  __syncthreads();

  const int row = tid >> 4;
  const int col = tid & 15;
  const int mylen = len_sh[row];
  const int ci = col * 20 + row;

  float hreg = 0.0f, hprev = 0.0f;

  // lane byte offset into an h slot for A-frag [data|tag] pair loads:
  // pairs laid out [c*16+row][128 pairs]; lane reads row (lane&15),
  // quarter (lane>>4): base = row*1024 + (lane>>4)*32, frag kt at +kt*128.
  const unsigned vh = (unsigned)((c * 16 + (lane & 15)) * 1024 + (lane >> 4) * 32);
  // per-EVEN-thread publish offset: row=tid>>4, colpair=(tid&15)>>1
  const unsigned pub_off =
      (unsigned)(((c * 16 + (tid >> 4)) * 128 + w * 8 + ((tid & 15) >> 1)) * 8);
  const float* xbase =
      x + ((size_t)c * 16 + (lane & 15)) * DIM + (lane >> 4) * 8;

  for (int t = 0; t < T_STEPS; ++t) {
    const int r0 = t * 5;
    // ======================= round A (cell gates) =======================
    {
      const float* xp = xbase + (size_t)t * BATCH * DIM;
      uint4v xf[8];
#pragma unroll
      for (int kt = 0; kt < 8; ++kt) {
        float4v xa = *(const float4v*)(xp + kt * 32);
        float4v xb = *(const float4v*)(xp + kt * 32 + 4);
        uint4v f;
        f.x = pack_bf16x2(xa.x, xa.y);
        f.y = pack_bf16x2(xa.z, xa.w);
        f.z = pack_bf16x2(xb.x, xb.y);
        f.w = pack_bf16x2(xb.z, xb.w);
        xf[kt] = f;
      }

      float4v a0 = {0.f, 0.f, 0.f, 0.f};
      float4v a1 = {0.f, 0.f, 0.f, 0.f};
      float4v a2 = {0.f, 0.f, 0.f, 0.f};
      // x-dependent MFMAs issue first: the MFMA pipe crunches them while
      // v0 polls / others wait at the barrier.
      if (v < 3) {
#pragma unroll
        for (int kt = 0; kt < 8; ++kt)
          a0 = __builtin_amdgcn_mfma_f32_16x16x32_bf16(as_s8(xf[kt]), Wf[1][kt], a0, 0, 0, 0);
      } else {
#pragma unroll
        for (int kt = 0; kt < 8; ++kt)
          a1 = __builtin_amdgcn_mfma_f32_16x16x32_bf16(as_s8(xf[kt]), Wf[1][kt], a1, 0, 0, 0);
#pragma unroll
        for (int kt = 0; kt < 8; ++kt)
          a2 = __builtin_amdgcn_mfma_f32_16x16x32_bf16(as_s8(xf[kt]), Wf[2][kt], a2, 0, 0, 0);
      }
      uint4v h0, h1, h2, h3, h4, h5, h6, h7;
      if (v == 0) {
        const unsigned char* ap =
            hbuf + (size_t)((r0 - 1) & 3) * SLOT_BYTES + vh;
        POLL8T(h0, h1, h2, h3, h4, h5, h6, h7, ap, (unsigned)r0);
        hsh[0][lane] = h0; hsh[1][lane] = h1; hsh[2][lane] = h2;
        hsh[3][lane] = h3; hsh[4][lane] = h4; hsh[5][lane] = h5;
        hsh[6][lane] = h6; hsh[7][lane] = h7;
      }
      __syncthreads();
      if (v != 0) {
        h0 = hsh[0][lane]; h1 = hsh[1][lane]; h2 = hsh[2][lane];
        h3 = hsh[3][lane]; h4 = hsh[4][lane]; h5 = hsh[5][lane];
        h6 = hsh[6][lane]; h7 = hsh[7][lane];
      }
      MFMA_K8(a0, Wf[0], h0, h1, h2, h3, h4, h5, h6, h7);
      {
        float* tp = &tiles[(v < 3) ? v : 3][(lane & 15) * 20 + (lane >> 4) * 4];
        *(float4v*)tp = a0;
        if (v == 3) {
          *(float4v*)&tiles[4][(lane & 15) * 20 + (lane >> 4) * 4] = a1;
          *(float4v*)&tiles[5][(lane & 15) * 20 + (lane >> 4) * 4] = a2;
        }
      }
      __syncthreads();
      float rp  = tiles[0][ci], zp = tiles[1][ci], lp = tiles[2][ci];
      float chv = tiles[3][ci], xcv = tiles[4][ci], xwv = tiles[5][ci];
      float r  = sigf(rp), z = sigf(zp), lg = sigf(lp);
      float n  = tanh_fast(xcv + r * chv) + lg * xwv;
      hreg = (1.0f - z) * hreg + z * n;
      // publish NOW: pair even/odd columns in-register, even threads store.
      {
        float hp = __shfl_xor(hreg, 1);
        if (!(tid & 1)) {
          unsigned char* pp = hbuf + (size_t)(r0 & 3) * SLOT_BYTES + pub_off;
          PUBLISH(pp, pack_bf16x2(hreg, hp), (unsigned)(r0 + 1));
        }
      }
    }
    // ======================= transition layers =======================
#pragma unroll
    for (int i = 0; i < NLAYERS; ++i) {
      const int ri = r0 + 1 + i;
      uint4v h0, h1, h2, h3, h4, h5, h6, h7;
      if (v == 0) {
        const unsigned char* ap =
            hbuf + (size_t)((ri - 1) & 3) * SLOT_BYTES + vh;
        POLL8T(h0, h1, h2, h3, h4, h5, h6, h7, ap, (unsigned)ri);
        hsh[0][lane] = h0; hsh[1][lane] = h1; hsh[2][lane] = h2;
        hsh[3][lane] = h3; hsh[4][lane] = h4; hsh[5][lane] = h5;
        hsh[6][lane] = h6; hsh[7][lane] = h7;
      }
      __syncthreads();
      if (v < 3) {
        if (v != 0) {
          h0 = hsh[0][lane]; h1 = hsh[1][lane]; h2 = hsh[2][lane];
          h3 = hsh[3][lane]; h4 = hsh[4][lane]; h5 = hsh[5][lane];
          h6 = hsh[6][lane]; h7 = hsh[7][lane];
        }
        float4v a = {0.f, 0.f, 0.f, 0.f};
        MFMA_K8(a, Wf[2 + i], h0, h1, h2, h3, h4, h5, h6, h7);
        *(float4v*)&tiles[v][(lane & 15) * 20 + (lane >> 4) * 4] = a;
      }
      __syncthreads();
      float rr = sigf(tiles[0][ci]);
      float zz = sigf(tiles[1][ci]);
      float nn = tanh_fast(rr * tiles[2][ci]);
      hreg = (1.0f - zz) * nn + zz * hreg;
      if (i == NLAYERS - 1) {
        const bool act = (t < mylen);
        float hv = act ? hreg : hprev;   // freeze h past sequence end
        float ov = act ? hreg : 0.0f;    // out = m ? hn : 0
        hreg = hv;
        hprev = hv;
        out[((size_t)t * BATCH + c * 16 + row) * HID + w * 16 + col] = ov;
      }
      {
        float hp = __shfl_xor(hreg, 1);
        if (!(tid & 1)) {
          unsigned char* pp = hbuf + (size_t)(ri & 3) * SLOT_BYTES + pub_off;
          PUBLISH(pp, pack_bf16x2(hreg, hp), (unsigned)(ri + 1));
        }
      }
    }
  }
}

extern "C" void kernel_launch(void* const* d_in, const int* in_sizes, int n_in,
                              void* d_out, int out_size, void* d_ws, size_t ws_size,
                              hipStream_t stream) {
  (void)in_sizes; (void)n_in; (void)out_size; (void)ws_size;
  const float* x        = (const float*)d_in[0];
  const int* lengths    = (const int*)d_in[1];
  const float* Wr       = (const float*)d_in[2];
  const float* Wz       = (const float*)d_in[3];
  const float* Wl       = (const float*)d_in[4];
  const float* Wt       = (const float*)d_in[5];
  const float* Cx       = (const float*)d_in[6];
  const float* Ch       = (const float*)d_in[7];
  const float* Tr       = (const float*)d_in[8];
  const float* Tz       = (const float*)d_in[9];
  const float* Tn       = (const float*)d_in[10];

  unsigned char* hbuf = (unsigned char*)d_ws;

  // Ring init: all slots zero. tag 0 == "round -1 published"; slot 3 data
  // (zeros) is exactly h0. Must re-run every launch (ws is re-poisoned).
  hipMemsetAsync(hbuf, 0x00, HBUF_BYTES, stream);

  rnn_main<<<dim3(128), dim3(256), 0, stream>>>(
      x, lengths, Wr, Wz, Wl, Wt, Cx, Ch, Tr, Tz, Tn,
      hbuf, (float*)d_out);
}